// Round 3
// baseline (701.059 us; speedup 1.0000x reference)
//
#include <hip/hip_runtime.h>

#define N_FIN 128
#define N_HID 16
#define N_OUT 12
#define NBLK 256          // blocks for hist/binwrite (fixed: region layout depends on it)
#define BN   128          // nodes per bucket (dl = dst & 127, bucket = dst >> 7)

// ---------- per-(block,bucket) histogram of dst>>7 ----------
__global__ __launch_bounds__(256) void k_hist(const int* __restrict__ dst,
                                              unsigned* __restrict__ hist,
                                              int E, int chunk, int NB) {
  __shared__ unsigned lh[1024];
  int t = threadIdx.x, blk = blockIdx.x;
  for (int b = t; b < NB; b += 256) lh[b] = 0u;
  __syncthreads();
  int lo = blk * chunk, hi = min(E, lo + chunk);
  for (int j = lo + t; j < hi; j += 256) atomicAdd(&lh[dst[j] >> 7], 1u);
  __syncthreads();
  for (int b = t; b < NB; b += 256) hist[(size_t)b * NBLK + blk] = lh[b];
}

// ---------- exclusive scan of hist (bucket-major) ----------
__global__ __launch_bounds__(256) void k_scan1(const unsigned* __restrict__ in,
                                               unsigned* __restrict__ out,
                                               unsigned* __restrict__ bsum, int M) {
  __shared__ unsigned s[256];
  int t = threadIdx.x, i = blockIdx.x * 256 + t;
  unsigned v = (i < M) ? in[i] : 0u;
  s[t] = v;
  __syncthreads();
#pragma unroll
  for (int off = 1; off < 256; off <<= 1) {
    unsigned y = (t >= off) ? s[t - off] : 0u;
    __syncthreads();
    s[t] += y;
    __syncthreads();
  }
  if (i < M) out[i] = s[t] - v;
  if (t == 255) bsum[blockIdx.x] = s[255];
}

__global__ __launch_bounds__(1024) void k_scan2(unsigned* __restrict__ bsum, int nb) {
  __shared__ unsigned s[1024];
  int t = threadIdx.x;
  unsigned v = (t < nb) ? bsum[t] : 0u;
  s[t] = v;
  __syncthreads();
#pragma unroll
  for (int off = 1; off < 1024; off <<= 1) {
    unsigned y = (t >= off) ? s[t - off] : 0u;
    __syncthreads();
    s[t] += y;
    __syncthreads();
  }
  if (t < nb) bsum[t] = s[t] - v;
}

__global__ __launch_bounds__(256) void k_scan3(unsigned* __restrict__ out,
                                               const unsigned* __restrict__ bsum, int M) {
  int i = blockIdx.x * 256 + threadIdx.x;
  if (i < M) out[i] += bsum[blockIdx.x];
}

// ---------- bin edges into bucket-major regions (sequential writes/block) ----------
__global__ __launch_bounds__(256) void k_binwrite(const int* __restrict__ src,
                                                  const int* __restrict__ dst,
                                                  const unsigned* __restrict__ base,
                                                  unsigned* __restrict__ entries,
                                                  int E, int chunk, int NB) {
  __shared__ unsigned cur[1024];
  int t = threadIdx.x, blk = blockIdx.x;
  for (int b = t; b < NB; b += 256) cur[b] = base[(size_t)b * NBLK + blk];
  __syncthreads();
  int lo = blk * chunk, hi = min(E, lo + chunk);
  for (int j = lo + t; j < hi; j += 256) {
    int d = dst[j];
    int b = d >> 7;
    unsigned pos = atomicAdd(&cur[b], 1u);
    entries[pos] = ((unsigned)src[j] << 7) | (unsigned)(d & (BN - 1));
  }
}

// ---------- degree per node from binned entries -> dinv ----------
__global__ __launch_bounds__(256) void k_degcnt(const unsigned* __restrict__ entries,
                                                const unsigned* __restrict__ base,
                                                float* __restrict__ dinv,
                                                int N, int NB, int E) {
  __shared__ unsigned cnt[BN];
  int t = threadIdx.x, b = blockIdx.x;
  if (t < BN) cnt[t] = 0u;
  __syncthreads();
  unsigned start = base[(size_t)b * NBLK];
  unsigned end = (b + 1 < NB) ? base[(size_t)(b + 1) * NBLK] : (unsigned)E;
  for (unsigned j = start + t; j < end; j += 256) atomicAdd(&cnt[entries[j] & (BN - 1)], 1u);
  __syncthreads();
  int node = b * BN + t;
  if (t < BN && node < N) dinv[node] = rsqrtf((float)(cnt[t] + 1u));
}

// ---------------- hs = dinv * (x @ W1), x:[N,128] W1:[128,16] ----------------
__global__ __launch_bounds__(256) void k_gemm1(const float* __restrict__ x,
                                               const float* __restrict__ W1,
                                               const float* __restrict__ dinv,
                                               float* __restrict__ hs, int N) {
  __shared__ float xs[16][132];
  __shared__ float wT[16][132];
  int t = threadIdx.x;
#pragma unroll
  for (int i = 0; i < 8; ++i) {
    int idx = t + i * 256;
    int k = idx >> 4, c = idx & 15;
    wT[c][k] = W1[idx];
  }
  int row0 = blockIdx.x * 16;
#pragma unroll
  for (int i = 0; i < 2; ++i) {
    int idx = t + i * 256;
    int r = idx >> 5, c4 = idx & 31;
    float4 v = make_float4(0.f, 0.f, 0.f, 0.f);
    if (row0 + r < N) v = *(const float4*)(x + (size_t)(row0 + r) * N_FIN + c4 * 4);
    *(float4*)&xs[r][c4 * 4] = v;
  }
  __syncthreads();
  int col = t & 15, r = t >> 4;
  float acc = 0.f;
#pragma unroll
  for (int kc = 0; kc < 32; ++kc) {
    float4 xv = *(const float4*)&xs[r][kc * 4];
    float4 wv = *(const float4*)&wT[col][kc * 4];
    acc += xv.x * wv.x + xv.y * wv.y + xv.z * wv.z + xv.w * wv.w;
  }
  int row = row0 + r;
  if (row < N) hs[(size_t)row * N_HID + col] = dinv[row] * acc;
}

// ------ layer1: bucket aggregation + self-loop + bias + relu + 16x12 GEMM -----
__global__ __launch_bounds__(256) void k_gagg1(const unsigned* __restrict__ entries,
                                               const unsigned* __restrict__ base,
                                               const float* __restrict__ hs,
                                               const float* __restrict__ dinv,
                                               const float* __restrict__ b1,
                                               const float* __restrict__ W2,
                                               float* __restrict__ hs2,
                                               int N, int NB, int E) {
  __shared__ float os[BN][N_HID];
  __shared__ unsigned es[256];
  __shared__ float w2s[N_HID][N_OUT];
  __shared__ float b1s[N_HID];
  int t = threadIdx.x, b = blockIdx.x;
  if (t < N_HID * N_OUT) w2s[t / N_OUT][t % N_OUT] = W2[t];
  if (t < N_HID) b1s[t] = b1[t];
  for (int i = t; i < BN * N_HID; i += 256) ((float*)os)[i] = 0.f;
  unsigned start = base[(size_t)b * NBLK];
  unsigned end = (b + 1 < NB) ? base[(size_t)(b + 1) * NBLK] : (unsigned)E;
  __syncthreads();
  int eg = t >> 4, c = t & 15;
  for (unsigned e0 = start; e0 < end; e0 += 256) {
    unsigned j = e0 + t;
    es[t] = (j < end) ? entries[j] : 0u;
    __syncthreads();
    int cnt = (int)min(256u, end - e0);
#pragma unroll 4
    for (int k = 0; k < 16; ++k) {
      int idx = k * 16 + eg;
      if (idx < cnt) {
        unsigned en = es[idx];
        int s = (int)(en >> 7), dl = (int)(en & (BN - 1));
        atomicAdd(&os[dl][c], hs[(size_t)s * N_HID + c]);
      }
    }
    __syncthreads();
  }
  int node0 = b * BN;
  // o = relu(dinv*(agg + self) + b1), in place
  for (int i = t; i < BN * N_HID; i += 256) {
    int dl = i >> 4, cc = i & 15;
    int node = node0 + dl;
    if (node < N) {
      float di = dinv[node];
      os[dl][cc] = fmaxf(di * (os[dl][cc] + hs[(size_t)node * N_HID + cc]) + b1s[cc], 0.f);
    }
  }
  __syncthreads();
  // hs2 = dinv * (o @ W2)
  for (int sdx = t; sdx < BN * N_OUT; sdx += 256) {
    int dl = sdx / N_OUT, c2 = sdx % N_OUT;
    int node = node0 + dl;
    if (node < N) {
      float acc = 0.f;
#pragma unroll
      for (int cc = 0; cc < N_HID; ++cc) acc += os[dl][cc] * w2s[cc][c2];
      hs2[(size_t)node * N_OUT + c2] = dinv[node] * acc;
    }
  }
}

// ------ layer2: bucket aggregation + self-loop + bias + log_softmax -----------
__global__ __launch_bounds__(256) void k_gagg2(const unsigned* __restrict__ entries,
                                               const unsigned* __restrict__ base,
                                               const float* __restrict__ hs2,
                                               const float* __restrict__ dinv,
                                               const float* __restrict__ b2,
                                               float* __restrict__ out,
                                               int N, int NB, int E) {
  __shared__ float os[BN][N_OUT];
  __shared__ float ls[BN];
  __shared__ unsigned es[256];
  __shared__ float b2s[N_OUT];
  int t = threadIdx.x, b = blockIdx.x;
  if (t < N_OUT) b2s[t] = b2[t];
  for (int i = t; i < BN * N_OUT; i += 256) ((float*)os)[i] = 0.f;
  unsigned start = base[(size_t)b * NBLK];
  unsigned end = (b + 1 < NB) ? base[(size_t)(b + 1) * NBLK] : (unsigned)E;
  __syncthreads();
  int eg = t >> 4, c = t & 15;
  for (unsigned e0 = start; e0 < end; e0 += 256) {
    unsigned j = e0 + t;
    es[t] = (j < end) ? entries[j] : 0u;
    __syncthreads();
    int cnt = (int)min(256u, end - e0);
#pragma unroll 4
    for (int k = 0; k < 16; ++k) {
      int idx = k * 16 + eg;
      if (idx < cnt && c < N_OUT) {
        unsigned en = es[idx];
        int s = (int)(en >> 7), dl = (int)(en & (BN - 1));
        atomicAdd(&os[dl][c], hs2[(size_t)s * N_OUT + c]);
      }
    }
    __syncthreads();
  }
  int node0 = b * BN;
  // z = dinv*(agg + self) + b2, in place
  for (int i = t; i < BN * N_OUT; i += 256) {
    int dl = i / N_OUT, cc = i % N_OUT;
    int node = node0 + dl;
    if (node < N) {
      float di = dinv[node];
      os[dl][cc] = di * (os[dl][cc] + hs2[(size_t)node * N_OUT + cc]) + b2s[cc];
    }
  }
  __syncthreads();
  if (t < BN && node0 + t < N) {
    float m = os[t][0];
#pragma unroll
    for (int j = 1; j < N_OUT; ++j) m = fmaxf(m, os[t][j]);
    float sum = 0.f;
#pragma unroll
    for (int j = 0; j < N_OUT; ++j) sum += __expf(os[t][j] - m);
    ls[t] = m + __logf(sum);
  }
  __syncthreads();
  for (int i = t; i < BN * N_OUT; i += 256) {
    int dl = i / N_OUT, cc = i % N_OUT;
    int node = node0 + dl;
    if (node < N) out[(size_t)node * N_OUT + cc] = os[dl][cc] - ls[dl];
  }
}

extern "C" void kernel_launch(void* const* d_in, const int* in_sizes, int n_in,
                              void* d_out, int out_size, void* d_ws, size_t ws_size,
                              hipStream_t stream) {
  const float* x  = (const float*)d_in[0];
  const int*   ei = (const int*)d_in[1];
  const float* W1 = (const float*)d_in[2];
  const float* b1 = (const float*)d_in[3];
  const float* W2 = (const float*)d_in[4];
  const float* b2 = (const float*)d_in[5];
  int N = in_sizes[0] / N_FIN;
  int E = in_sizes[1] / 2;
  const int* src = ei;
  const int* dst = ei + E;

  int NB = (N + BN - 1) / BN;            // 782 buckets
  int M  = NB * NBLK;                    // hist/base table size
  int chunk = (E + NBLK - 1) / NBLK;     // edges per binning block
  int sb = (M + 255) / 256;              // scan blocks (== NB)

  // ws: [hist M][base M][bsum 1024][dinv N][hs N*16][hs2 N*12][entries E]
  char* ws = (char*)d_ws;
  unsigned* hist    = (unsigned*)ws;  ws += (size_t)M * 4;
  unsigned* base    = (unsigned*)ws;  ws += (size_t)M * 4;
  unsigned* bsum    = (unsigned*)ws;  ws += 4096;
  float*    dinv    = (float*)ws;     ws += (size_t)N * 4;
  float*    hs      = (float*)ws;     ws += (size_t)N * N_HID * 4;
  float*    hs2     = (float*)ws;     ws += (size_t)N * N_OUT * 4;
  unsigned* entries = (unsigned*)ws;

  k_hist    <<<NBLK, 256, 0, stream>>>(dst, hist, E, chunk, NB);
  k_scan1   <<<sb, 256, 0, stream>>>(hist, base, bsum, M);
  k_scan2   <<<1, 1024, 0, stream>>>(bsum, sb);
  k_scan3   <<<sb, 256, 0, stream>>>(base, bsum, M);
  k_binwrite<<<NBLK, 256, 0, stream>>>(src, dst, base, entries, E, chunk, NB);
  k_degcnt  <<<NB, 256, 0, stream>>>(entries, base, dinv, N, NB, E);
  k_gemm1   <<<(N + 15) / 16, 256, 0, stream>>>(x, W1, dinv, hs, N);
  k_gagg1   <<<NB, 256, 0, stream>>>(entries, base, hs, dinv, b1, W2, hs2, N, NB, E);
  k_gagg2   <<<NB, 256, 0, stream>>>(entries, base, hs2, dinv, b2, (float*)d_out, N, NB, E);
}

// Round 4
// 198.058 us; speedup vs baseline: 3.5397x; 3.5397x over previous
//
#include <hip/hip_runtime.h>

#define N_FIN 128
#define N_HID 16
#define N_OUT 12
#define H2S   16          // hs2 row stride (padded to one 64B line)
#define NBLK  256         // blocks for hist/binwrite (region layout depends on it)
#define BN    128         // nodes per bucket (dl = dst & 127, bucket = dst >> 7)

// ---------- per-(block,bucket) histogram of dst>>7 ----------
__global__ __launch_bounds__(256) void k_hist(const int* __restrict__ dst,
                                              unsigned* __restrict__ hist,
                                              int E, int chunk, int NB) {
  __shared__ unsigned lh[1024];
  int t = threadIdx.x, blk = blockIdx.x;
  for (int b = t; b < NB; b += 256) lh[b] = 0u;
  __syncthreads();
  int lo = blk * chunk, hi = min(E, lo + chunk);
  for (int j = lo + t; j < hi; j += 256) atomicAdd(&lh[dst[j] >> 7], 1u);
  __syncthreads();
  for (int b = t; b < NB; b += 256) hist[(size_t)b * NBLK + blk] = lh[b];
}

// ---------- exclusive scan of hist (bucket-major) ----------
__global__ __launch_bounds__(256) void k_scan1(const unsigned* __restrict__ in,
                                               unsigned* __restrict__ out,
                                               unsigned* __restrict__ bsum, int M) {
  __shared__ unsigned s[256];
  int t = threadIdx.x, i = blockIdx.x * 256 + t;
  unsigned v = (i < M) ? in[i] : 0u;
  s[t] = v;
  __syncthreads();
#pragma unroll
  for (int off = 1; off < 256; off <<= 1) {
    unsigned y = (t >= off) ? s[t - off] : 0u;
    __syncthreads();
    s[t] += y;
    __syncthreads();
  }
  if (i < M) out[i] = s[t] - v;
  if (t == 255) bsum[blockIdx.x] = s[255];
}

__global__ __launch_bounds__(1024) void k_scan2(unsigned* __restrict__ bsum, int nb) {
  __shared__ unsigned s[1024];
  int t = threadIdx.x;
  unsigned v = (t < nb) ? bsum[t] : 0u;
  s[t] = v;
  __syncthreads();
#pragma unroll
  for (int off = 1; off < 1024; off <<= 1) {
    unsigned y = (t >= off) ? s[t - off] : 0u;
    __syncthreads();
    s[t] += y;
    __syncthreads();
  }
  if (t < nb) bsum[t] = s[t] - v;
}

__global__ __launch_bounds__(256) void k_scan3(unsigned* __restrict__ out,
                                               const unsigned* __restrict__ bsum, int M) {
  int i = blockIdx.x * 256 + threadIdx.x;
  if (i < M) out[i] += bsum[blockIdx.x];
}

// ---------- bin edges into bucket-major regions (sequential writes/block) ----------
__global__ __launch_bounds__(256) void k_binwrite(const int* __restrict__ src,
                                                  const int* __restrict__ dst,
                                                  const unsigned* __restrict__ base,
                                                  unsigned* __restrict__ entries,
                                                  int E, int chunk, int NB) {
  __shared__ unsigned cur[1024];
  int t = threadIdx.x, blk = blockIdx.x;
  for (int b = t; b < NB; b += 256) cur[b] = base[(size_t)b * NBLK + blk];
  __syncthreads();
  int lo = blk * chunk, hi = min(E, lo + chunk);
  for (int j = lo + t; j < hi; j += 256) {
    int d = dst[j];
    int b = d >> 7;
    unsigned pos = atomicAdd(&cur[b], 1u);
    entries[pos] = ((unsigned)src[j] << 7) | (unsigned)(d & (BN - 1));
  }
}

// ---------- per-bucket: histogram dl -> deg/dinv/row_start, then CSR order ----------
__global__ __launch_bounds__(256) void k_bucket_csr(const unsigned* __restrict__ entries,
                                                    const unsigned* __restrict__ base,
                                                    unsigned* __restrict__ row_start,
                                                    unsigned* __restrict__ deg,
                                                    float* __restrict__ dinv,
                                                    unsigned* __restrict__ esrc,
                                                    int N, int NB, int E) {
  __shared__ unsigned cnt[BN];
  __shared__ unsigned cur[BN];
  int t = threadIdx.x, b = blockIdx.x;
  if (t < BN) cnt[t] = 0u;
  __syncthreads();
  unsigned start = base[(size_t)b * NBLK];
  unsigned end = (b + 1 < NB) ? base[(size_t)(b + 1) * NBLK] : (unsigned)E;
  for (unsigned j = start + t; j < end; j += 256) atomicAdd(&cnt[entries[j] & (BN - 1)], 1u);
  __syncthreads();
  // exclusive scan of cnt (Hillis-Steele over 128)
  unsigned v = (t < BN) ? cnt[t] : 0u;
  if (t < BN) cur[t] = v;
  __syncthreads();
#pragma unroll
  for (int off = 1; off < BN; off <<= 1) {
    unsigned y = (t < BN && t >= off) ? cur[t - off] : 0u;
    __syncthreads();
    if (t < BN) cur[t] += y;
    __syncthreads();
  }
  if (t < BN) {
    unsigned excl = cur[t] - v;
    cur[t] = excl;
    int node = b * BN + t;
    if (node < N) {
      row_start[node] = start + excl;
      deg[node] = v;
      dinv[node] = rsqrtf((float)(v + 1u));
    }
  }
  __syncthreads();
  for (unsigned j = start + t; j < end; j += 256) {
    unsigned en = entries[j];
    unsigned dl = en & (BN - 1);
    unsigned p = atomicAdd(&cur[dl], 1u);
    esrc[start + p] = en >> 7;
  }
}

// ---------------- hs = dinv * (x @ W1), x:[N,128] W1:[128,16] ----------------
__global__ __launch_bounds__(256) void k_gemm1(const float* __restrict__ x,
                                               const float* __restrict__ W1,
                                               const float* __restrict__ dinv,
                                               float* __restrict__ hs, int N) {
  __shared__ float xs[16][132];
  __shared__ float wT[16][132];
  int t = threadIdx.x;
#pragma unroll
  for (int i = 0; i < 8; ++i) {
    int idx = t + i * 256;
    int k = idx >> 4, c = idx & 15;
    wT[c][k] = W1[idx];
  }
  int row0 = blockIdx.x * 16;
#pragma unroll
  for (int i = 0; i < 2; ++i) {
    int idx = t + i * 256;
    int r = idx >> 5, c4 = idx & 31;
    float4 v = make_float4(0.f, 0.f, 0.f, 0.f);
    if (row0 + r < N) v = *(const float4*)(x + (size_t)(row0 + r) * N_FIN + c4 * 4);
    *(float4*)&xs[r][c4 * 4] = v;
  }
  __syncthreads();
  int col = t & 15, r = t >> 4;
  float acc = 0.f;
#pragma unroll
  for (int kc = 0; kc < 32; ++kc) {
    float4 xv = *(const float4*)&xs[r][kc * 4];
    float4 wv = *(const float4*)&wT[col][kc * 4];
    acc += xv.x * wv.x + xv.y * wv.y + xv.z * wv.z + xv.w * wv.w;
  }
  int row = row0 + r;
  if (row < N) hs[(size_t)row * N_HID + col] = dinv[row] * acc;
}

// ------ layer1: CSR gather + self-loop + bias + relu + 16x12 GEMM -------------
__global__ __launch_bounds__(256) void k_gagg1(const unsigned* __restrict__ esrc,
                                               const unsigned* __restrict__ row_start,
                                               const unsigned* __restrict__ deg,
                                               const float* __restrict__ hs,
                                               const float* __restrict__ dinv,
                                               const float* __restrict__ b1,
                                               const float* __restrict__ W2,
                                               float* __restrict__ hs2, int N) {
  __shared__ float os[16][N_HID + 1];
  __shared__ float w2s[N_HID][N_OUT];
  __shared__ float b1s[N_HID];
  int t = threadIdx.x;
  if (t < N_HID * N_OUT) w2s[t / N_OUT][t % N_OUT] = W2[t];
  if (t < N_HID) b1s[t] = b1[t];
  __syncthreads();
  int nl = t >> 4, c = t & 15;
  int node = blockIdx.x * 16 + nl;
  float o = 0.f;
  if (node < N) {
    unsigned s0 = row_start[node], dn = deg[node];
    float a0 = 0.f, a1 = 0.f, a2 = 0.f, a3 = 0.f;
    unsigned j = 0;
    for (; j + 4 <= dn; j += 4) {
      unsigned e0 = esrc[s0 + j], e1 = esrc[s0 + j + 1];
      unsigned e2 = esrc[s0 + j + 2], e3 = esrc[s0 + j + 3];
      a0 += hs[(size_t)e0 * N_HID + c];
      a1 += hs[(size_t)e1 * N_HID + c];
      a2 += hs[(size_t)e2 * N_HID + c];
      a3 += hs[(size_t)e3 * N_HID + c];
    }
    for (; j < dn; ++j) a0 += hs[(size_t)esrc[s0 + j] * N_HID + c];
    float acc = (a0 + a1) + (a2 + a3);
    o = fmaxf(dinv[node] * (acc + hs[(size_t)node * N_HID + c]) + b1s[c], 0.f);
  }
  os[nl][c] = o;
  __syncthreads();
  if (t < 16 * N_OUT) {
    int n2 = t / N_OUT, c2 = t % N_OUT;
    int node2 = blockIdx.x * 16 + n2;
    if (node2 < N) {
      float s = 0.f;
#pragma unroll
      for (int cc = 0; cc < N_HID; ++cc) s += os[n2][cc] * w2s[cc][c2];
      hs2[(size_t)node2 * H2S + c2] = dinv[node2] * s;
    }
  }
}

// ------ layer2: CSR gather + self-loop + bias + log_softmax -------------------
__global__ __launch_bounds__(256) void k_gagg2(const unsigned* __restrict__ esrc,
                                               const unsigned* __restrict__ row_start,
                                               const unsigned* __restrict__ deg,
                                               const float* __restrict__ hs2,
                                               const float* __restrict__ dinv,
                                               const float* __restrict__ b2,
                                               float* __restrict__ out, int N) {
  __shared__ float zs[16][13];
  __shared__ float ls[16];
  __shared__ float b2s[N_OUT];
  int t = threadIdx.x;
  if (t < N_OUT) b2s[t] = b2[t];
  __syncthreads();
  int nl = t >> 4, c = t & 15;
  int node = blockIdx.x * 16 + nl;
  if (node < N && c < N_OUT) {
    unsigned s0 = row_start[node], dn = deg[node];
    float a0 = 0.f, a1 = 0.f, a2 = 0.f, a3 = 0.f;
    unsigned j = 0;
    for (; j + 4 <= dn; j += 4) {
      unsigned e0 = esrc[s0 + j], e1 = esrc[s0 + j + 1];
      unsigned e2 = esrc[s0 + j + 2], e3 = esrc[s0 + j + 3];
      a0 += hs2[(size_t)e0 * H2S + c];
      a1 += hs2[(size_t)e1 * H2S + c];
      a2 += hs2[(size_t)e2 * H2S + c];
      a3 += hs2[(size_t)e3 * H2S + c];
    }
    for (; j < dn; ++j) a0 += hs2[(size_t)esrc[s0 + j] * H2S + c];
    float acc = (a0 + a1) + (a2 + a3);
    zs[nl][c] = dinv[node] * (acc + hs2[(size_t)node * H2S + c]) + b2s[c];
  }
  __syncthreads();
  if (c == 0 && node < N) {
    float m = zs[nl][0];
#pragma unroll
    for (int jj = 1; jj < N_OUT; ++jj) m = fmaxf(m, zs[nl][jj]);
    float sum = 0.f;
#pragma unroll
    for (int jj = 0; jj < N_OUT; ++jj) sum += __expf(zs[nl][jj] - m);
    ls[nl] = m + __logf(sum);
  }
  __syncthreads();
  if (node < N && c < N_OUT) out[(size_t)node * N_OUT + c] = zs[nl][c] - ls[nl];
}

extern "C" void kernel_launch(void* const* d_in, const int* in_sizes, int n_in,
                              void* d_out, int out_size, void* d_ws, size_t ws_size,
                              hipStream_t stream) {
  const float* x  = (const float*)d_in[0];
  const int*   ei = (const int*)d_in[1];
  const float* W1 = (const float*)d_in[2];
  const float* b1 = (const float*)d_in[3];
  const float* W2 = (const float*)d_in[4];
  const float* b2 = (const float*)d_in[5];
  int N = in_sizes[0] / N_FIN;
  int E = in_sizes[1] / 2;
  const int* src = ei;
  const int* dst = ei + E;

  int NB = (N + BN - 1) / BN;            // 782 buckets
  int M  = NB * NBLK;                    // hist/base table size
  int chunk = (E + NBLK - 1) / NBLK;     // edges per binning block
  int sb = (M + 255) / 256;              // scan blocks

  // ws: [hist M][base M][bsum 1024][dinv N][deg N][row_start N]
  //     [big: entries E  (later aliased by hs N*16 + hs2 N*16)][esrc E]
  char* ws = (char*)d_ws;
  unsigned* hist      = (unsigned*)ws;  ws += (size_t)M * 4;
  unsigned* base      = (unsigned*)ws;  ws += (size_t)M * 4;
  unsigned* bsum      = (unsigned*)ws;  ws += 4096;
  float*    dinv      = (float*)ws;     ws += (size_t)N * 4;
  unsigned* deg       = (unsigned*)ws;  ws += (size_t)N * 4;
  unsigned* row_start = (unsigned*)ws;  ws += (size_t)N * 4;
  size_t big_bytes = (size_t)E * 4;
  size_t hs_bytes  = (size_t)N * N_HID * 4 + (size_t)N * H2S * 4;
  if (hs_bytes > big_bytes) big_bytes = hs_bytes;
  unsigned* entries = (unsigned*)ws;
  float*    hs      = (float*)ws;                              // aliases entries (dead after csr)
  float*    hs2     = (float*)(ws + (size_t)N * N_HID * 4);
  ws += big_bytes;
  unsigned* esrc    = (unsigned*)ws;

  k_hist      <<<NBLK, 256, 0, stream>>>(dst, hist, E, chunk, NB);
  k_scan1     <<<sb, 256, 0, stream>>>(hist, base, bsum, M);
  k_scan2     <<<1, 1024, 0, stream>>>(bsum, sb);
  k_scan3     <<<sb, 256, 0, stream>>>(base, bsum, M);
  k_binwrite  <<<NBLK, 256, 0, stream>>>(src, dst, base, entries, E, chunk, NB);
  k_bucket_csr<<<NB, 256, 0, stream>>>(entries, base, row_start, deg, dinv, esrc, N, NB, E);
  k_gemm1     <<<(N + 15) / 16, 256, 0, stream>>>(x, W1, dinv, hs, N);   // overwrites entries
  k_gagg1     <<<(N + 15) / 16, 256, 0, stream>>>(esrc, row_start, deg, hs, dinv, b1, W2, hs2, N);
  k_gagg2     <<<(N + 15) / 16, 256, 0, stream>>>(esrc, row_start, deg, hs2, dinv, b2, (float*)d_out, N);
}